// Round 1
// baseline (615.421 us; speedup 1.0000x reference)
//
#include <hip/hip_runtime.h>
#include <hip/hip_bf16.h>

#define NNODES 50000
#define NEDGES 800000
#define NFEAT 128
#define NHID 128
#define NCLASS 10
#define NGRAPHS 256

typedef __attribute__((ext_vector_type(8))) short short8;
typedef __attribute__((ext_vector_type(4))) float floatx4;

__device__ __forceinline__ float bf2f(unsigned short u) {
    union { unsigned i; float f; } c; c.i = ((unsigned)u) << 16; return c.f;
}
__device__ __forceinline__ unsigned short f2bf(float f) {
    union { float f; unsigned i; } c; c.f = f;
    unsigned x = c.i;
    unsigned r = (x + 0x7fffu + ((x >> 16) & 1u)) >> 16;
    return (unsigned short)r;
}

// ---------------- CSR build ----------------
__global__ void k_count(const int* __restrict__ dst, const int* __restrict__ batch,
                        int* __restrict__ deg, int* __restrict__ gcnt) {
    int gid = blockIdx.x * blockDim.x + threadIdx.x;
    if (gid < NEDGES) atomicAdd(&deg[dst[gid]], 1);
    if (gid < NNODES) atomicAdd(&gcnt[batch[gid]], 1);
}

__global__ __launch_bounds__(1024) void k_scan(const int* __restrict__ deg,
                                               int* __restrict__ row_ptr,
                                               int* __restrict__ cursor,
                                               const int* __restrict__ gcnt,
                                               int* __restrict__ gstart) {
    __shared__ int wsum[16];
    __shared__ int tot_s;
    int tid = threadIdx.x;
    int lane = tid & 63;
    int w = tid >> 6;
    int carry = 0;
    for (int base = 0; base < NNODES; base += 1024) {
        int i = base + tid;
        int v = (i < NNODES) ? deg[i] : 0;
        int x = v;
        #pragma unroll
        for (int d = 1; d < 64; d <<= 1) {
            int y = __shfl_up(x, d);
            if (lane >= d) x += y;
        }
        if (lane == 63) wsum[w] = x;
        __syncthreads();
        if (tid == 0) {
            int s = 0;
            #pragma unroll
            for (int k = 0; k < 16; ++k) { int t2 = wsum[k]; wsum[k] = s; s += t2; }
            tot_s = s;
        }
        __syncthreads();
        if (i < NNODES) {
            int excl = carry + wsum[w] + x - v;
            row_ptr[i] = excl;
            cursor[i] = excl;
        }
        carry += tot_s;
        __syncthreads();
    }
    if (tid == 0) {
        row_ptr[NNODES] = carry;
        int s = 0;
        for (int g = 0; g < NGRAPHS; ++g) { gstart[g] = s; s += gcnt[g]; }
        gstart[NGRAPHS] = s;
    }
}

__global__ void k_fill(const int* __restrict__ src, const int* __restrict__ dst,
                       int* __restrict__ cursor, int* __restrict__ esrc) {
    int gid = blockIdx.x * blockDim.x + threadIdx.x;
    if (gid < NEDGES) {
        int d = dst[gid];
        int pos = atomicAdd(&cursor[d], 1);
        esrc[pos] = src[gid];
    }
}

// ---------------- bf16 conversion of x and all 6 W matrices ----------------
__global__ void k_cvt(const float* __restrict__ x,
                      const float* __restrict__ w0, const float* __restrict__ w1,
                      const float* __restrict__ w2, const float* __restrict__ w3,
                      const float* __restrict__ w4, const float* __restrict__ w5,
                      unsigned short* __restrict__ xb, unsigned short* __restrict__ wb) {
    int gid = blockIdx.x * blockDim.x + threadIdx.x;
    const int NX = NNODES * NFEAT;
    if (gid < NX) {
        xb[gid] = f2bf(x[gid]);
    } else {
        int j = gid - NX;  // < 6*16384
        int m = j >> 14;
        int o = j & 16383;
        const float* w = (m == 0) ? w0 : (m == 1) ? w1 : (m == 2) ? w2
                       : (m == 3) ? w3 : (m == 4) ? w4 : w5;
        wb[j] = f2bf(w[o]);
    }
}

// ---------------- scatter-mean as CSR gather: wave per node ----------------
__global__ __launch_bounds__(256) void k_agg(const unsigned short* __restrict__ feat,
                                             const int* __restrict__ row_ptr,
                                             const int* __restrict__ esrc,
                                             unsigned short* __restrict__ agg) {
    int w = threadIdx.x >> 6;
    int l = threadIdx.x & 63;
    int n = blockIdx.x * 4 + w;
    if (n >= NNODES) return;
    int beg = row_ptr[n], end = row_ptr[n + 1];
    float a0 = 0.f, a1 = 0.f;
    const unsigned* feat32 = (const unsigned*)feat;  // 2 bf16 per dword, row stride 64
    for (int e = beg; e < end; ++e) {
        int s = esrc[e];
        unsigned v = feat32[s * 64 + l];
        a0 += bf2f((unsigned short)(v & 0xffffu));
        a1 += bf2f((unsigned short)(v >> 16));
    }
    float inv = 1.0f / (float)max(end - beg, 1);
    unsigned o = ((unsigned)f2bf(a0 * inv)) | (((unsigned)f2bf(a1 * inv)) << 16);
    ((unsigned*)agg)[n * 64 + l] = o;
}

// ---------------- fused dual-matvec GEMM: C = [agg|feat] @ [Wn|Ws]^T, +bias, relu ----
// M=50000 (16 rows/wave, 64/block), N=128, K=256. mfma_f32_16x16x32_bf16.
__global__ __launch_bounds__(256) void k_gemm(const unsigned short* __restrict__ A1,
                                              const unsigned short* __restrict__ A2,
                                              const unsigned short* __restrict__ Bn,
                                              const unsigned short* __restrict__ Bs,
                                              const float* __restrict__ bias,
                                              unsigned short* __restrict__ out) {
    int w = threadIdx.x >> 6;
    int l = threadIdx.x & 63;
    int r = l & 15;       // row-in-tile for A, col-in-tile for B/C
    int gk = l >> 4;      // k-group (8 elements each)
    int m0 = blockIdx.x * 64 + w * 16;
    int row = m0 + r;
    if (row >= NNODES) row = NNODES - 1;  // clamp loads; stores guarded

    floatx4 zero = {0.f, 0.f, 0.f, 0.f};
    floatx4 acc[8];
    #pragma unroll
    for (int i = 0; i < 8; ++i) acc[i] = zero;

    #pragma unroll
    for (int kt = 0; kt < 8; ++kt) {
        int kk = (kt & 3) * 32 + gk * 8;
        const unsigned short* Ap = (kt < 4 ? A1 : A2) + row * 128 + kk;
        short8 af = *(const short8*)Ap;
        const unsigned short* Bbase = (kt < 4 ? Bn : Bs);
        #pragma unroll
        for (int nt = 0; nt < 8; ++nt) {
            short8 bfr = *(const short8*)(Bbase + (nt * 16 + r) * 128 + kk);
            acc[nt] = __builtin_amdgcn_mfma_f32_16x16x32_bf16(af, bfr, acc[nt], 0, 0, 0);
        }
    }

    // C/D layout: col = lane&15 (=r), row-in-tile = (lane>>4)*4 + j
    #pragma unroll
    for (int nt = 0; nt < 8; ++nt) {
        int o = nt * 16 + r;
        float b = bias[o];
        #pragma unroll
        for (int j = 0; j < 4; ++j) {
            int mrow = m0 + gk * 4 + j;
            if (mrow < NNODES) {
                float v = acc[nt][j] + b;
                v = v > 0.f ? v : 0.f;
                out[mrow * 128 + o] = f2bf(v);
            }
        }
    }
}

// ---------------- mean pool per graph (batch sorted -> contiguous ranges) ----------
__global__ __launch_bounds__(128) void k_pool(const unsigned short* __restrict__ h,
                                              const int* __restrict__ gstart,
                                              float* __restrict__ g) {
    int gi = blockIdx.x;
    int f = threadIdx.x;
    int s = gstart[gi], e = gstart[gi + 1];
    float acc = 0.f;
    for (int n = s; n < e; ++n) acc += bf2f(h[n * 128 + f]);
    g[gi * 128 + f] = acc / (float)max(e - s, 1);
}

// ---------------- head: logits + log_softmax (f32) ----------------
__global__ __launch_bounds__(128) void k_head(const float* __restrict__ g,
                                              const float* __restrict__ Wlin,
                                              const float* __restrict__ blin,
                                              float* __restrict__ out) {
    int gi = blockIdx.x;
    __shared__ float gl[128];
    __shared__ float lg[NCLASS];
    int t = threadIdx.x;
    gl[t] = g[gi * 128 + t];
    __syncthreads();
    if (t < NCLASS) {
        float a = blin[t];
        #pragma unroll 16
        for (int i = 0; i < 128; ++i) a += gl[i] * Wlin[t * 128 + i];
        lg[t] = a;
    }
    __syncthreads();
    if (t == 0) {
        float m = lg[0];
        for (int k = 1; k < NCLASS; ++k) m = fmaxf(m, lg[k]);
        float s = 0.f;
        for (int k = 0; k < NCLASS; ++k) s += expf(lg[k] - m);
        float ls = logf(s) + m;
        for (int k = 0; k < NCLASS; ++k) out[gi * NCLASS + k] = lg[k] - ls;
    }
}

extern "C" void kernel_launch(void* const* d_in, const int* in_sizes, int n_in,
                              void* d_out, int out_size, void* d_ws, size_t ws_size,
                              hipStream_t stream) {
    const float* x    = (const float*)d_in[0];
    const int*   ei   = (const int*)d_in[1];
    const int*   src  = ei;
    const int*   dst  = ei + NEDGES;
    const int*   batch= (const int*)d_in[2];
    const float* W1n  = (const float*)d_in[3];
    const float* b1   = (const float*)d_in[4];
    const float* W1s  = (const float*)d_in[5];
    const float* W2n  = (const float*)d_in[6];
    const float* b2   = (const float*)d_in[7];
    const float* W2s  = (const float*)d_in[8];
    const float* W3n  = (const float*)d_in[9];
    const float* b3   = (const float*)d_in[10];
    const float* W3s  = (const float*)d_in[11];
    const float* Wlin = (const float*)d_in[12];
    const float* blin = (const float*)d_in[13];
    float* out = (float*)d_out;

    char* p = (char*)d_ws;
    auto alloc = [&](size_t bytes) -> void* {
        void* r = (void*)p;
        p += (bytes + 255) & ~(size_t)255;
        return r;
    };
    unsigned short* xb   = (unsigned short*)alloc((size_t)NNODES * NFEAT * 2);
    unsigned short* hA   = (unsigned short*)alloc((size_t)NNODES * NHID * 2);
    unsigned short* hB   = (unsigned short*)alloc((size_t)NNODES * NHID * 2);
    unsigned short* agg  = (unsigned short*)alloc((size_t)NNODES * NHID * 2);
    unsigned short* wb   = (unsigned short*)alloc((size_t)6 * 16384 * 2);
    int* deg     = (int*)alloc((size_t)NNODES * 4);
    int* gcnt    = (int*)alloc((size_t)NGRAPHS * 4);
    int* row_ptr = (int*)alloc((size_t)(NNODES + 1) * 4);
    int* cursor  = (int*)alloc((size_t)(NNODES + 1) * 4);
    int* gstart  = (int*)alloc((size_t)(NGRAPHS + 1) * 4);
    int* esrc    = (int*)alloc((size_t)NEDGES * 4);
    float* gpool = (float*)alloc((size_t)NGRAPHS * NHID * 4);

    hipMemsetAsync(deg, 0, (size_t)NNODES * 4, stream);
    hipMemsetAsync(gcnt, 0, (size_t)NGRAPHS * 4, stream);

    // CSR build
    k_count<<<(NEDGES + 255) / 256, 256, 0, stream>>>(dst, batch, deg, gcnt);
    k_scan<<<1, 1024, 0, stream>>>(deg, row_ptr, cursor, gcnt, gstart);
    k_fill<<<(NEDGES + 255) / 256, 256, 0, stream>>>(src, dst, cursor, esrc);

    // convert x + weights to bf16
    {
        int total = NNODES * NFEAT + 6 * 16384;
        k_cvt<<<(total + 255) / 256, 256, 0, stream>>>(x, W1n, W1s, W2n, W2s, W3n, W3s, xb, wb);
    }

    const int aggGrid  = (NNODES + 3) / 4;
    const int gemmGrid = (NNODES + 63) / 64;

    // layer 1
    k_agg<<<aggGrid, 256, 0, stream>>>(xb, row_ptr, esrc, agg);
    k_gemm<<<gemmGrid, 256, 0, stream>>>(agg, xb, wb + 0 * 16384, wb + 1 * 16384, b1, hA);
    // layer 2
    k_agg<<<aggGrid, 256, 0, stream>>>(hA, row_ptr, esrc, agg);
    k_gemm<<<gemmGrid, 256, 0, stream>>>(agg, hA, wb + 2 * 16384, wb + 3 * 16384, b2, hB);
    // layer 3
    k_agg<<<aggGrid, 256, 0, stream>>>(hB, row_ptr, esrc, agg);
    k_gemm<<<gemmGrid, 256, 0, stream>>>(agg, hB, wb + 4 * 16384, wb + 5 * 16384, b3, hA);

    // pool + head
    k_pool<<<NGRAPHS, 128, 0, stream>>>(hA, gstart, gpool);
    k_head<<<NGRAPHS, 128, 0, stream>>>(gpool, Wlin, blin, out);
}

// Round 2
// 389.092 us; speedup vs baseline: 1.5817x; 1.5817x over previous
//
#include <hip/hip_runtime.h>
#include <hip/hip_bf16.h>

#define NNODES 50000
#define NEDGES 800000
#define NFEAT 128
#define NHID 128
#define NCLASS 10
#define NGRAPHS 256

#define NB 391   // (NNODES+127)/128 buckets of 128 nodes
#define HB 128   // histogram/scatter blocks

typedef __attribute__((ext_vector_type(8))) short short8;
typedef __attribute__((ext_vector_type(4))) float floatx4;

__device__ __forceinline__ float bf2f(unsigned short u) {
    union { unsigned i; float f; } c; c.i = ((unsigned)u) << 16; return c.f;
}
__device__ __forceinline__ unsigned short f2bf(float f) {
    union { float f; unsigned i; } c; c.f = f;
    unsigned x = c.i;
    unsigned r = (x + 0x7fffu + ((x >> 16) & 1u)) >> 16;
    return (unsigned short)r;
}

// ---------------- atomic-free CSR build: two-level counting sort ----------------
// Pass 1: per-block LDS histogram over NB buckets (bucket = dst>>7), no global atomics.
__global__ __launch_bounds__(256) void k_hist(const int* __restrict__ dst,
                                              int* __restrict__ hist) {
    __shared__ int lh[NB];
    int tid = threadIdx.x;
    for (int b = tid; b < NB; b += 256) lh[b] = 0;
    __syncthreads();
    for (int i = blockIdx.x * 256 + tid; i < NEDGES; i += HB * 256)
        atomicAdd(&lh[dst[i] >> 7], 1);
    __syncthreads();
    for (int b = tid; b < NB; b += 256) hist[blockIdx.x * NB + b] = lh[b];
}

// Pass 2: bucket totals, exclusive scan -> boff, per-(block,bucket) bases.
__global__ __launch_bounds__(512) void k_scan2(const int* __restrict__ hist,
                                               int* __restrict__ base,
                                               int* __restrict__ boff,
                                               int* __restrict__ row_ptr) {
    __shared__ int tot[NB + 1];
    int tid = threadIdx.x;
    if (tid < NB) {
        int s = 0;
        for (int b = 0; b < HB; ++b) s += hist[b * NB + tid];
        tot[tid] = s;
    }
    __syncthreads();
    if (tid == 0) {
        int s = 0;
        for (int i = 0; i < NB; ++i) { int t = tot[i]; tot[i] = s; s += t; }
        tot[NB] = s;                 // == NEDGES
        row_ptr[NNODES] = s;
    }
    __syncthreads();
    if (tid <= NB) boff[tid] = tot[tid];
    if (tid < NB) {
        int s = tot[tid];
        for (int b = 0; b < HB; ++b) { base[b * NB + tid] = s; s += hist[b * NB + tid]; }
    }
}

// Pass 3: scatter edges into bucket-sorted ebuf; LDS cursors seeded from bases.
// Same per-block edge set as k_hist (same grid-stride), so bases line up.
__global__ __launch_bounds__(256) void k_scatter(const int* __restrict__ src,
                                                 const int* __restrict__ dst,
                                                 const int* __restrict__ base,
                                                 unsigned* __restrict__ ebuf) {
    __shared__ int cur[NB];
    int tid = threadIdx.x;
    for (int b = tid; b < NB; b += 256) cur[b] = base[blockIdx.x * NB + b];
    __syncthreads();
    for (int i = blockIdx.x * 256 + tid; i < NEDGES; i += HB * 256) {
        int d = dst[i];
        int bin = d >> 7;
        int pos = atomicAdd(&cur[bin], 1);                    // LDS atomic
        ebuf[pos] = (unsigned)src[i] | ((unsigned)(d & 127) << 16);
    }
}

// Pass 4: per-bucket local CSR (128 nodes) fully in LDS.
__global__ __launch_bounds__(256) void k_bcsr(const unsigned* __restrict__ ebuf,
                                              const int* __restrict__ boff,
                                              int* __restrict__ row_ptr,
                                              int* __restrict__ esrc) {
    __shared__ int deg[128];
    __shared__ int curs[128];
    int tid = threadIdx.x;
    int b = blockIdx.x;
    int s = boff[b], e = boff[b + 1];
    if (tid < 128) deg[tid] = 0;
    __syncthreads();
    for (int i = s + tid; i < e; i += 256) atomicAdd(&deg[ebuf[i] >> 16], 1);
    __syncthreads();
    if (tid == 0) {
        int run = s;
        for (int i = 0; i < 128; ++i) { curs[i] = run; run += deg[i]; }
    }
    __syncthreads();
    if (tid < 128) {
        int node = b * 128 + tid;
        if (node < NNODES) row_ptr[node] = curs[tid];
    }
    __syncthreads();
    for (int i = s + tid; i < e; i += 256) {
        unsigned pk = ebuf[i];
        int pos = atomicAdd(&curs[pk >> 16], 1);              // LDS atomic
        esrc[pos] = (int)(pk & 0xffffu);
    }
}

// batch is sorted: graph ranges via binary search, no atomics.
__global__ __launch_bounds__(320) void k_gstart(const int* __restrict__ batch,
                                                int* __restrict__ gstart) {
    int g = threadIdx.x;
    if (g > NGRAPHS) return;
    int lo = 0, hi = NNODES;
    while (lo < hi) { int mid = (lo + hi) >> 1; if (batch[mid] < g) lo = mid + 1; else hi = mid; }
    gstart[g] = lo;
}

// ---------------- bf16 conversion of x and all 6 W matrices ----------------
__global__ void k_cvt(const float* __restrict__ x,
                      const float* __restrict__ w0, const float* __restrict__ w1,
                      const float* __restrict__ w2, const float* __restrict__ w3,
                      const float* __restrict__ w4, const float* __restrict__ w5,
                      unsigned short* __restrict__ xb, unsigned short* __restrict__ wb) {
    int gid = blockIdx.x * blockDim.x + threadIdx.x;
    const int NX = NNODES * NFEAT;
    if (gid < NX) {
        xb[gid] = f2bf(x[gid]);
    } else {
        int j = gid - NX;  // < 6*16384
        int m = j >> 14;
        int o = j & 16383;
        const float* w = (m == 0) ? w0 : (m == 1) ? w1 : (m == 2) ? w2
                       : (m == 3) ? w3 : (m == 4) ? w4 : w5;
        wb[j] = f2bf(w[o]);
    }
}

// ---------------- scatter-mean as CSR gather: wave per node, 2x unrolled ----------
__global__ __launch_bounds__(256) void k_agg(const unsigned short* __restrict__ feat,
                                             const int* __restrict__ row_ptr,
                                             const int* __restrict__ esrc,
                                             unsigned short* __restrict__ agg) {
    int w = threadIdx.x >> 6;
    int l = threadIdx.x & 63;
    int n = blockIdx.x * 4 + w;
    if (n >= NNODES) return;
    int beg = row_ptr[n], end = row_ptr[n + 1];
    float a0 = 0.f, a1 = 0.f;
    const unsigned* feat32 = (const unsigned*)feat;  // 2 bf16 per dword, row stride 64
    int e = beg;
    for (; e + 2 <= end; e += 2) {
        int s0 = esrc[e], s1 = esrc[e + 1];
        unsigned v0 = feat32[s0 * 64 + l];
        unsigned v1 = feat32[s1 * 64 + l];
        a0 += bf2f((unsigned short)(v0 & 0xffffu)) + bf2f((unsigned short)(v1 & 0xffffu));
        a1 += bf2f((unsigned short)(v0 >> 16)) + bf2f((unsigned short)(v1 >> 16));
    }
    if (e < end) {
        unsigned v = feat32[esrc[e] * 64 + l];
        a0 += bf2f((unsigned short)(v & 0xffffu));
        a1 += bf2f((unsigned short)(v >> 16));
    }
    float inv = 1.0f / (float)max(end - beg, 1);
    unsigned o = ((unsigned)f2bf(a0 * inv)) | (((unsigned)f2bf(a1 * inv)) << 16);
    ((unsigned*)agg)[n * 64 + l] = o;
}

// ---------------- fused dual-matvec GEMM: C = [agg|feat] @ [Wn|Ws]^T, +bias, relu ----
// M=50000 (16 rows/wave, 64/block), N=128, K=256. mfma_f32_16x16x32_bf16.
__global__ __launch_bounds__(256) void k_gemm(const unsigned short* __restrict__ A1,
                                              const unsigned short* __restrict__ A2,
                                              const unsigned short* __restrict__ Bn,
                                              const unsigned short* __restrict__ Bs,
                                              const float* __restrict__ bias,
                                              unsigned short* __restrict__ out) {
    int w = threadIdx.x >> 6;
    int l = threadIdx.x & 63;
    int r = l & 15;       // row-in-tile for A, col-in-tile for B/C
    int gk = l >> 4;      // k-group (8 elements each)
    int m0 = blockIdx.x * 64 + w * 16;
    int row = m0 + r;
    if (row >= NNODES) row = NNODES - 1;  // clamp loads; stores guarded

    floatx4 zero = {0.f, 0.f, 0.f, 0.f};
    floatx4 acc[8];
    #pragma unroll
    for (int i = 0; i < 8; ++i) acc[i] = zero;

    #pragma unroll
    for (int kt = 0; kt < 8; ++kt) {
        int kk = (kt & 3) * 32 + gk * 8;
        const unsigned short* Ap = (kt < 4 ? A1 : A2) + row * 128 + kk;
        short8 af = *(const short8*)Ap;
        const unsigned short* Bbase = (kt < 4 ? Bn : Bs);
        #pragma unroll
        for (int nt = 0; nt < 8; ++nt) {
            short8 bfr = *(const short8*)(Bbase + (nt * 16 + r) * 128 + kk);
            acc[nt] = __builtin_amdgcn_mfma_f32_16x16x32_bf16(af, bfr, acc[nt], 0, 0, 0);
        }
    }

    // C/D layout: col = lane&15 (=r), row-in-tile = (lane>>4)*4 + j
    #pragma unroll
    for (int nt = 0; nt < 8; ++nt) {
        int o = nt * 16 + r;
        float b = bias[o];
        #pragma unroll
        for (int j = 0; j < 4; ++j) {
            int mrow = m0 + gk * 4 + j;
            if (mrow < NNODES) {
                float v = acc[nt][j] + b;
                v = v > 0.f ? v : 0.f;
                out[mrow * 128 + o] = f2bf(v);
            }
        }
    }
}

// ---------------- mean pool per graph (batch sorted -> contiguous ranges) ----------
__global__ __launch_bounds__(128) void k_pool(const unsigned short* __restrict__ h,
                                              const int* __restrict__ gstart,
                                              float* __restrict__ g) {
    int gi = blockIdx.x;
    int f = threadIdx.x;
    int s = gstart[gi], e = gstart[gi + 1];
    float acc = 0.f;
    for (int n = s; n < e; ++n) acc += bf2f(h[n * 128 + f]);
    g[gi * 128 + f] = acc / (float)max(e - s, 1);
}

// ---------------- head: logits + log_softmax (f32) ----------------
__global__ __launch_bounds__(128) void k_head(const float* __restrict__ g,
                                              const float* __restrict__ Wlin,
                                              const float* __restrict__ blin,
                                              float* __restrict__ out) {
    int gi = blockIdx.x;
    __shared__ float gl[128];
    __shared__ float lg[NCLASS];
    int t = threadIdx.x;
    gl[t] = g[gi * 128 + t];
    __syncthreads();
    if (t < NCLASS) {
        float a = blin[t];
        #pragma unroll 16
        for (int i = 0; i < 128; ++i) a += gl[i] * Wlin[t * 128 + i];
        lg[t] = a;
    }
    __syncthreads();
    if (t == 0) {
        float m = lg[0];
        for (int k = 1; k < NCLASS; ++k) m = fmaxf(m, lg[k]);
        float s = 0.f;
        for (int k = 0; k < NCLASS; ++k) s += expf(lg[k] - m);
        float ls = logf(s) + m;
        for (int k = 0; k < NCLASS; ++k) out[gi * NCLASS + k] = lg[k] - ls;
    }
}

extern "C" void kernel_launch(void* const* d_in, const int* in_sizes, int n_in,
                              void* d_out, int out_size, void* d_ws, size_t ws_size,
                              hipStream_t stream) {
    const float* x    = (const float*)d_in[0];
    const int*   ei   = (const int*)d_in[1];
    const int*   src  = ei;
    const int*   dst  = ei + NEDGES;
    const int*   batch= (const int*)d_in[2];
    const float* W1n  = (const float*)d_in[3];
    const float* b1   = (const float*)d_in[4];
    const float* W1s  = (const float*)d_in[5];
    const float* W2n  = (const float*)d_in[6];
    const float* b2   = (const float*)d_in[7];
    const float* W2s  = (const float*)d_in[8];
    const float* W3n  = (const float*)d_in[9];
    const float* b3   = (const float*)d_in[10];
    const float* W3s  = (const float*)d_in[11];
    const float* Wlin = (const float*)d_in[12];
    const float* blin = (const float*)d_in[13];
    float* out = (float*)d_out;

    char* p = (char*)d_ws;
    auto alloc = [&](size_t bytes) -> void* {
        void* r = (void*)p;
        p += (bytes + 255) & ~(size_t)255;
        return r;
    };
    unsigned short* xb   = (unsigned short*)alloc((size_t)NNODES * NFEAT * 2);
    unsigned short* hA   = (unsigned short*)alloc((size_t)NNODES * NHID * 2);
    unsigned short* hB   = (unsigned short*)alloc((size_t)NNODES * NHID * 2);
    unsigned short* agg  = (unsigned short*)alloc((size_t)NNODES * NHID * 2);
    unsigned short* wb   = (unsigned short*)alloc((size_t)6 * 16384 * 2);
    int* hist    = (int*)alloc((size_t)HB * NB * 4);
    int* base    = (int*)alloc((size_t)HB * NB * 4);
    int* boff    = (int*)alloc((size_t)(NB + 1) * 4);
    int* row_ptr = (int*)alloc((size_t)(NNODES + 1) * 4);
    int* gstart  = (int*)alloc((size_t)(NGRAPHS + 1) * 4);
    unsigned* ebuf = (unsigned*)alloc((size_t)NEDGES * 4);
    int* esrc    = (int*)alloc((size_t)NEDGES * 4);
    float* gpool = (float*)alloc((size_t)NGRAPHS * NHID * 4);

    // CSR build (atomic-free counting sort) + graph ranges
    k_hist<<<HB, 256, 0, stream>>>(dst, hist);
    k_scan2<<<1, 512, 0, stream>>>(hist, base, boff, row_ptr);
    k_scatter<<<HB, 256, 0, stream>>>(src, dst, base, ebuf);
    k_bcsr<<<NB, 256, 0, stream>>>(ebuf, boff, row_ptr, esrc);
    k_gstart<<<1, 320, 0, stream>>>(batch, gstart);

    // convert x + weights to bf16
    {
        int total = NNODES * NFEAT + 6 * 16384;
        k_cvt<<<(total + 255) / 256, 256, 0, stream>>>(x, W1n, W1s, W2n, W2s, W3n, W3s, xb, wb);
    }

    const int aggGrid  = (NNODES + 3) / 4;
    const int gemmGrid = (NNODES + 63) / 64;

    // layer 1
    k_agg<<<aggGrid, 256, 0, stream>>>(xb, row_ptr, esrc, agg);
    k_gemm<<<gemmGrid, 256, 0, stream>>>(agg, xb, wb + 0 * 16384, wb + 1 * 16384, b1, hA);
    // layer 2
    k_agg<<<aggGrid, 256, 0, stream>>>(hA, row_ptr, esrc, agg);
    k_gemm<<<gemmGrid, 256, 0, stream>>>(agg, hA, wb + 2 * 16384, wb + 3 * 16384, b2, hB);
    // layer 3
    k_agg<<<aggGrid, 256, 0, stream>>>(hB, row_ptr, esrc, agg);
    k_gemm<<<gemmGrid, 256, 0, stream>>>(agg, hB, wb + 4 * 16384, wb + 5 * 16384, b3, hA);

    // pool + head
    k_pool<<<NGRAPHS, 128, 0, stream>>>(hA, gstart, gpool);
    k_head<<<NGRAPHS, 128, 0, stream>>>(gpool, Wlin, blin, out);
}

// Round 3
// 280.209 us; speedup vs baseline: 2.1963x; 1.3886x over previous
//
#include <hip/hip_runtime.h>
#include <hip/hip_bf16.h>

#define NNODES 50000
#define NEDGES 800000
#define NFEAT 128
#define NHID 128
#define NCLASS 10
#define NGRAPHS 256

#define NB 391   // (NNODES+127)/128 buckets of 128 nodes
#define HB 128   // histogram/scatter blocks

typedef __attribute__((ext_vector_type(8))) short short8;
typedef __attribute__((ext_vector_type(4))) float floatx4;

__device__ __forceinline__ float bf2f(unsigned short u) {
    union { unsigned i; float f; } c; c.i = ((unsigned)u) << 16; return c.f;
}
__device__ __forceinline__ unsigned short f2bf(float f) {
    union { float f; unsigned i; } c; c.f = f;
    unsigned x = c.i;
    unsigned r = (x + 0x7fffu + ((x >> 16) & 1u)) >> 16;
    return (unsigned short)r;
}
__device__ __forceinline__ float blo(unsigned v) { return bf2f((unsigned short)(v & 0xffffu)); }
__device__ __forceinline__ float bhi(unsigned v) { return bf2f((unsigned short)(v >> 16)); }

// ---------------- atomic-free CSR build: two-level counting sort ----------------
__global__ __launch_bounds__(256) void k_hist(const int* __restrict__ dst,
                                              int* __restrict__ hist) {
    __shared__ int lh[NB];
    int tid = threadIdx.x;
    for (int b = tid; b < NB; b += 256) lh[b] = 0;
    __syncthreads();
    for (int i = blockIdx.x * 256 + tid; i < NEDGES; i += HB * 256)
        atomicAdd(&lh[dst[i] >> 7], 1);
    __syncthreads();
    for (int b = tid; b < NB; b += 256) hist[blockIdx.x * NB + b] = lh[b];
}

// Pass 2: bucket totals, exclusive scan -> boff, per-(block,bucket) bases.
// Also computes graph start offsets via binary search on sorted batch.
__global__ __launch_bounds__(512) void k_scan2(const int* __restrict__ hist,
                                               int* __restrict__ base,
                                               int* __restrict__ boff,
                                               int* __restrict__ row_ptr,
                                               const int* __restrict__ batch,
                                               int* __restrict__ gstart) {
    __shared__ int tot[NB + 1];
    int tid = threadIdx.x;
    if (tid <= NGRAPHS) {
        int lo = 0, hi = NNODES;
        while (lo < hi) { int mid = (lo + hi) >> 1; if (batch[mid] < tid) lo = mid + 1; else hi = mid; }
        gstart[tid] = lo;
    }
    if (tid < NB) {
        int s = 0;
        for (int b = 0; b < HB; ++b) s += hist[b * NB + tid];
        tot[tid] = s;
    }
    __syncthreads();
    if (tid == 0) {
        int s = 0;
        for (int i = 0; i < NB; ++i) { int t = tot[i]; tot[i] = s; s += t; }
        tot[NB] = s;
        row_ptr[NNODES] = s;
    }
    __syncthreads();
    if (tid <= NB) boff[tid] = tot[tid];
    if (tid < NB) {
        int s = tot[tid];
        for (int b = 0; b < HB; ++b) { base[b * NB + tid] = s; s += hist[b * NB + tid]; }
    }
}

// Pass 3: scatter edges into bucket-sorted ebuf; LDS cursors seeded from bases.
__global__ __launch_bounds__(256) void k_scatter(const int* __restrict__ src,
                                                 const int* __restrict__ dst,
                                                 const int* __restrict__ base,
                                                 unsigned* __restrict__ ebuf) {
    __shared__ int cur[NB];
    int tid = threadIdx.x;
    for (int b = tid; b < NB; b += 256) cur[b] = base[blockIdx.x * NB + b];
    __syncthreads();
    for (int i = blockIdx.x * 256 + tid; i < NEDGES; i += HB * 256) {
        int d = dst[i];
        int bin = d >> 7;
        int pos = atomicAdd(&cur[bin], 1);                    // LDS atomic
        ebuf[pos] = (unsigned)src[i] | ((unsigned)(d & 127) << 16);
    }
}

// Pass 4: per-bucket local CSR (128 nodes) fully in LDS.
__global__ __launch_bounds__(256) void k_bcsr(const unsigned* __restrict__ ebuf,
                                              const int* __restrict__ boff,
                                              int* __restrict__ row_ptr,
                                              int* __restrict__ esrc) {
    __shared__ int deg[128];
    __shared__ int curs[128];
    int tid = threadIdx.x;
    int b = blockIdx.x;
    int s = boff[b], e = boff[b + 1];
    if (tid < 128) deg[tid] = 0;
    __syncthreads();
    for (int i = s + tid; i < e; i += 256) atomicAdd(&deg[ebuf[i] >> 16], 1);
    __syncthreads();
    if (tid == 0) {
        int run = s;
        for (int i = 0; i < 128; ++i) { curs[i] = run; run += deg[i]; }
    }
    __syncthreads();
    if (tid < 128) {
        int node = b * 128 + tid;
        if (node < NNODES) row_ptr[node] = curs[tid];
    }
    __syncthreads();
    for (int i = s + tid; i < e; i += 256) {
        unsigned pk = ebuf[i];
        int pos = atomicAdd(&curs[pk >> 16], 1);              // LDS atomic
        esrc[pos] = (int)(pk & 0xffffu);
    }
}

// ---------------- bf16 conversion of x and all 6 W matrices ----------------
__global__ void k_cvt(const float* __restrict__ x,
                      const float* __restrict__ w0, const float* __restrict__ w1,
                      const float* __restrict__ w2, const float* __restrict__ w3,
                      const float* __restrict__ w4, const float* __restrict__ w5,
                      unsigned short* __restrict__ xb, unsigned short* __restrict__ wb) {
    int gid = blockIdx.x * blockDim.x + threadIdx.x;
    const int NX = NNODES * NFEAT;
    if (gid < NX) {
        xb[gid] = f2bf(x[gid]);
    } else {
        int j = gid - NX;  // < 6*16384
        int m = j >> 14;
        int o = j & 16383;
        const float* w = (m == 0) ? w0 : (m == 1) ? w1 : (m == 2) ? w2
                       : (m == 3) ? w3 : (m == 4) ? w4 : w5;
        wb[j] = f2bf(w[o]);
    }
}

// ---------------- scatter-mean as CSR gather: wave per node ----------------
// Edge indices loaded coalesced per-lane, broadcast via shfl; 4 gathers in flight.
__global__ __launch_bounds__(256) void k_agg(const unsigned short* __restrict__ feat,
                                             const int* __restrict__ row_ptr,
                                             const int* __restrict__ esrc,
                                             unsigned short* __restrict__ agg) {
    int w = threadIdx.x >> 6;
    int l = threadIdx.x & 63;
    int n = blockIdx.x * 4 + w;
    if (n >= NNODES) return;
    int beg = row_ptr[n], end = row_ptr[n + 1];
    int nb = end - beg;
    const unsigned* feat32 = (const unsigned*)feat;  // 2 bf16 per dword, row stride 64
    float a0 = 0.f, a1 = 0.f;
    for (int base = 0; base < nb; base += 64) {
        int rem = nb - base;
        int cnt = rem < 64 ? rem : 64;
        int myidx = (l < cnt) ? esrc[beg + base + l] : 0;   // coalesced index load
        int j = 0;
        for (; j + 4 <= cnt; j += 4) {
            int s0 = __shfl(myidx, j);
            int s1 = __shfl(myidx, j + 1);
            int s2 = __shfl(myidx, j + 2);
            int s3 = __shfl(myidx, j + 3);
            unsigned v0 = feat32[s0 * 64 + l];
            unsigned v1 = feat32[s1 * 64 + l];
            unsigned v2 = feat32[s2 * 64 + l];
            unsigned v3 = feat32[s3 * 64 + l];
            a0 += (blo(v0) + blo(v1)) + (blo(v2) + blo(v3));
            a1 += (bhi(v0) + bhi(v1)) + (bhi(v2) + bhi(v3));
        }
        for (; j < cnt; ++j) {
            int s0 = __shfl(myidx, j);
            unsigned v0 = feat32[s0 * 64 + l];
            a0 += blo(v0);
            a1 += bhi(v0);
        }
    }
    float inv = 1.0f / (float)max(nb, 1);
    unsigned o = ((unsigned)f2bf(a0 * inv)) | (((unsigned)f2bf(a1 * inv)) << 16);
    ((unsigned*)agg)[n * 64 + l] = o;
}

// ---------------- fused dual-matvec GEMM: C = [agg|feat] @ [Wn|Ws]^T, +bias, relu ----
__global__ __launch_bounds__(256) void k_gemm(const unsigned short* __restrict__ A1,
                                              const unsigned short* __restrict__ A2,
                                              const unsigned short* __restrict__ Bn,
                                              const unsigned short* __restrict__ Bs,
                                              const float* __restrict__ bias,
                                              unsigned short* __restrict__ out) {
    int w = threadIdx.x >> 6;
    int l = threadIdx.x & 63;
    int r = l & 15;       // row-in-tile for A, col-in-tile for B/C
    int gk = l >> 4;      // k-group (8 elements each)
    int m0 = blockIdx.x * 64 + w * 16;
    int row = m0 + r;
    if (row >= NNODES) row = NNODES - 1;  // clamp loads; stores guarded

    floatx4 zero = {0.f, 0.f, 0.f, 0.f};
    floatx4 acc[8];
    #pragma unroll
    for (int i = 0; i < 8; ++i) acc[i] = zero;

    #pragma unroll
    for (int kt = 0; kt < 8; ++kt) {
        int kk = (kt & 3) * 32 + gk * 8;
        const unsigned short* Ap = (kt < 4 ? A1 : A2) + row * 128 + kk;
        short8 af = *(const short8*)Ap;
        const unsigned short* Bbase = (kt < 4 ? Bn : Bs);
        #pragma unroll
        for (int nt = 0; nt < 8; ++nt) {
            short8 bfr = *(const short8*)(Bbase + (nt * 16 + r) * 128 + kk);
            acc[nt] = __builtin_amdgcn_mfma_f32_16x16x32_bf16(af, bfr, acc[nt], 0, 0, 0);
        }
    }

    #pragma unroll
    for (int nt = 0; nt < 8; ++nt) {
        int o = nt * 16 + r;
        float b = bias[o];
        #pragma unroll
        for (int j = 0; j < 4; ++j) {
            int mrow = m0 + gk * 4 + j;
            if (mrow < NNODES) {
                float v = acc[nt][j] + b;
                v = v > 0.f ? v : 0.f;
                out[mrow * 128 + o] = f2bf(v);
            }
        }
    }
}

// ---------------- mean pool: 8 partial-sum blocks per graph ----------------
__global__ __launch_bounds__(256) void k_pool(const unsigned short* __restrict__ h,
                                              const int* __restrict__ gstart,
                                              float* __restrict__ part) {
    int g = blockIdx.x >> 3;
    int c = blockIdx.x & 7;
    int s = gstart[g], e = gstart[g + 1];
    int len = e - s;
    int cs = s + (len * c) / 8;
    int ce = s + (len * (c + 1)) / 8;
    int w = threadIdx.x >> 6;
    int l = threadIdx.x & 63;
    const unsigned* h32 = (const unsigned*)h;
    float a0 = 0.f, a1 = 0.f;
    for (int n = cs + w; n < ce; n += 4) {
        unsigned v = h32[n * 64 + l];
        a0 += blo(v);
        a1 += bhi(v);
    }
    __shared__ float red[4][128];
    red[w][2 * l] = a0;
    red[w][2 * l + 1] = a1;
    __syncthreads();
    if (w == 0) {
        float r0 = (red[0][2 * l] + red[1][2 * l]) + (red[2][2 * l] + red[3][2 * l]);
        float r1 = (red[0][2 * l + 1] + red[1][2 * l + 1]) + (red[2][2 * l + 1] + red[3][2 * l + 1]);
        float* dst = part + (size_t)(g * 8 + c) * 128;
        dst[2 * l] = r0;
        dst[2 * l + 1] = r1;
    }
}

// ---------------- head: reduce partials, logits + log_softmax (f32) ----------------
__global__ __launch_bounds__(128) void k_head(const float* __restrict__ part,
                                              const int* __restrict__ gstart,
                                              const float* __restrict__ Wlin,
                                              const float* __restrict__ blin,
                                              float* __restrict__ out) {
    int gi = blockIdx.x;
    __shared__ float gl[128];
    __shared__ float lg[NCLASS];
    int t = threadIdx.x;
    float s = 0.f;
    #pragma unroll
    for (int c = 0; c < 8; ++c) s += part[(size_t)(gi * 8 + c) * 128 + t];
    int len = gstart[gi + 1] - gstart[gi];
    gl[t] = s / (float)max(len, 1);
    __syncthreads();
    if (t < NCLASS) {
        float a = blin[t];
        #pragma unroll 16
        for (int i = 0; i < 128; ++i) a += gl[i] * Wlin[t * 128 + i];
        lg[t] = a;
    }
    __syncthreads();
    if (t == 0) {
        float m = lg[0];
        for (int k = 1; k < NCLASS; ++k) m = fmaxf(m, lg[k]);
        float sum = 0.f;
        for (int k = 0; k < NCLASS; ++k) sum += expf(lg[k] - m);
        float ls = logf(sum) + m;
        for (int k = 0; k < NCLASS; ++k) out[gi * NCLASS + k] = lg[k] - ls;
    }
}

extern "C" void kernel_launch(void* const* d_in, const int* in_sizes, int n_in,
                              void* d_out, int out_size, void* d_ws, size_t ws_size,
                              hipStream_t stream) {
    const float* x    = (const float*)d_in[0];
    const int*   ei   = (const int*)d_in[1];
    const int*   src  = ei;
    const int*   dst  = ei + NEDGES;
    const int*   batch= (const int*)d_in[2];
    const float* W1n  = (const float*)d_in[3];
    const float* b1   = (const float*)d_in[4];
    const float* W1s  = (const float*)d_in[5];
    const float* W2n  = (const float*)d_in[6];
    const float* b2   = (const float*)d_in[7];
    const float* W2s  = (const float*)d_in[8];
    const float* W3n  = (const float*)d_in[9];
    const float* b3   = (const float*)d_in[10];
    const float* W3s  = (const float*)d_in[11];
    const float* Wlin = (const float*)d_in[12];
    const float* blin = (const float*)d_in[13];
    float* out = (float*)d_out;

    char* p = (char*)d_ws;
    auto alloc = [&](size_t bytes) -> void* {
        void* r = (void*)p;
        p += (bytes + 255) & ~(size_t)255;
        return r;
    };
    unsigned short* xb   = (unsigned short*)alloc((size_t)NNODES * NFEAT * 2);
    unsigned short* hA   = (unsigned short*)alloc((size_t)NNODES * NHID * 2);
    unsigned short* hB   = (unsigned short*)alloc((size_t)NNODES * NHID * 2);
    unsigned short* agg  = (unsigned short*)alloc((size_t)NNODES * NHID * 2);
    unsigned short* wb   = (unsigned short*)alloc((size_t)6 * 16384 * 2);
    int* hist    = (int*)alloc((size_t)HB * NB * 4);
    int* base    = (int*)alloc((size_t)HB * NB * 4);
    int* boff    = (int*)alloc((size_t)(NB + 1) * 4);
    int* row_ptr = (int*)alloc((size_t)(NNODES + 1) * 4);
    int* gstart  = (int*)alloc((size_t)(NGRAPHS + 1) * 4);
    unsigned* ebuf = (unsigned*)alloc((size_t)NEDGES * 4);
    int* esrc    = (int*)alloc((size_t)NEDGES * 4);
    float* part  = (float*)alloc((size_t)NGRAPHS * 8 * NHID * 4);

    // CSR build (atomic-free counting sort) + graph ranges
    k_hist<<<HB, 256, 0, stream>>>(dst, hist);
    k_scan2<<<1, 512, 0, stream>>>(hist, base, boff, row_ptr, batch, gstart);
    k_scatter<<<HB, 256, 0, stream>>>(src, dst, base, ebuf);
    k_bcsr<<<NB, 256, 0, stream>>>(ebuf, boff, row_ptr, esrc);

    // convert x + weights to bf16
    {
        int total = NNODES * NFEAT + 6 * 16384;
        k_cvt<<<(total + 255) / 256, 256, 0, stream>>>(x, W1n, W1s, W2n, W2s, W3n, W3s, xb, wb);
    }

    const int aggGrid  = (NNODES + 3) / 4;
    const int gemmGrid = (NNODES + 63) / 64;

    // layer 1
    k_agg<<<aggGrid, 256, 0, stream>>>(xb, row_ptr, esrc, agg);
    k_gemm<<<gemmGrid, 256, 0, stream>>>(agg, xb, wb + 0 * 16384, wb + 1 * 16384, b1, hA);
    // layer 2
    k_agg<<<aggGrid, 256, 0, stream>>>(hA, row_ptr, esrc, agg);
    k_gemm<<<gemmGrid, 256, 0, stream>>>(agg, hA, wb + 2 * 16384, wb + 3 * 16384, b2, hB);
    // layer 3
    k_agg<<<aggGrid, 256, 0, stream>>>(hB, row_ptr, esrc, agg);
    k_gemm<<<gemmGrid, 256, 0, stream>>>(agg, hB, wb + 4 * 16384, wb + 5 * 16384, b3, hA);

    // pool + head
    k_pool<<<NGRAPHS * 8, 256, 0, stream>>>(hA, gstart, part);
    k_head<<<NGRAPHS, 128, 0, stream>>>(part, gstart, Wlin, blin, out);
}

// Round 4
// 267.346 us; speedup vs baseline: 2.3020x; 1.0481x over previous
//
#include <hip/hip_runtime.h>
#include <hip/hip_bf16.h>

#define NNODES 50000
#define NEDGES 800000
#define NFEAT 128
#define NHID 128
#define NCLASS 10
#define NGRAPHS 256

#define NB 391   // (NNODES+127)/128 buckets of 128 nodes
#define HB 128   // histogram/scatter blocks

typedef __attribute__((ext_vector_type(8))) short short8;
typedef __attribute__((ext_vector_type(4))) float floatx4;

__device__ __forceinline__ float bf2f(unsigned short u) {
    union { unsigned i; float f; } c; c.i = ((unsigned)u) << 16; return c.f;
}
__device__ __forceinline__ unsigned short f2bf(float f) {
    union { float f; unsigned i; } c; c.f = f;
    unsigned x = c.i;
    unsigned r = (x + 0x7fffu + ((x >> 16) & 1u)) >> 16;
    return (unsigned short)r;
}
__device__ __forceinline__ float blo(unsigned v) { return bf2f((unsigned short)(v & 0xffffu)); }
__device__ __forceinline__ float bhi(unsigned v) { return bf2f((unsigned short)(v >> 16)); }

// ---------------- atomic-free CSR build: two-level counting sort ----------------
__global__ __launch_bounds__(256) void k_hist(const int* __restrict__ dst,
                                              int* __restrict__ hist) {
    __shared__ int lh[NB];
    int tid = threadIdx.x;
    for (int b = tid; b < NB; b += 256) lh[b] = 0;
    __syncthreads();
    for (int i = blockIdx.x * 256 + tid; i < NEDGES; i += HB * 256)
        atomicAdd(&lh[dst[i] >> 7], 1);
    __syncthreads();
    for (int b = tid; b < NB; b += 256) hist[blockIdx.x * NB + b] = lh[b];
}

// Pass 2: bucket totals, exclusive scan -> boff, per-(block,bucket) bases.
// Also computes graph start offsets via binary search on sorted batch.
__global__ __launch_bounds__(512) void k_scan2(const int* __restrict__ hist,
                                               int* __restrict__ base,
                                               int* __restrict__ boff,
                                               int* __restrict__ row_ptr,
                                               const int* __restrict__ batch,
                                               int* __restrict__ gstart) {
    __shared__ int tot[NB + 1];
    int tid = threadIdx.x;
    if (tid <= NGRAPHS) {
        int lo = 0, hi = NNODES;
        while (lo < hi) { int mid = (lo + hi) >> 1; if (batch[mid] < tid) lo = mid + 1; else hi = mid; }
        gstart[tid] = lo;
    }
    if (tid < NB) {
        int s = 0;
        for (int b = 0; b < HB; ++b) s += hist[b * NB + tid];
        tot[tid] = s;
    }
    __syncthreads();
    if (tid == 0) {
        int s = 0;
        for (int i = 0; i < NB; ++i) { int t = tot[i]; tot[i] = s; s += t; }
        tot[NB] = s;
        row_ptr[NNODES] = s;
    }
    __syncthreads();
    if (tid <= NB) boff[tid] = tot[tid];
    if (tid < NB) {
        int s = tot[tid];
        for (int b = 0; b < HB; ++b) { base[b * NB + tid] = s; s += hist[b * NB + tid]; }
    }
}

// Pass 3: scatter edges into bucket-sorted ebuf; LDS cursors seeded from bases.
__global__ __launch_bounds__(256) void k_scatter(const int* __restrict__ src,
                                                 const int* __restrict__ dst,
                                                 const int* __restrict__ base,
                                                 unsigned* __restrict__ ebuf) {
    __shared__ int cur[NB];
    int tid = threadIdx.x;
    for (int b = tid; b < NB; b += 256) cur[b] = base[blockIdx.x * NB + b];
    __syncthreads();
    for (int i = blockIdx.x * 256 + tid; i < NEDGES; i += HB * 256) {
        int d = dst[i];
        int bin = d >> 7;
        int pos = atomicAdd(&cur[bin], 1);                    // LDS atomic
        ebuf[pos] = (unsigned)src[i] | ((unsigned)(d & 127) << 16);
    }
}

// Pass 4: per-bucket local CSR (128 nodes) fully in LDS.
__global__ __launch_bounds__(256) void k_bcsr(const unsigned* __restrict__ ebuf,
                                              const int* __restrict__ boff,
                                              int* __restrict__ row_ptr,
                                              int* __restrict__ esrc) {
    __shared__ int deg[128];
    __shared__ int curs[128];
    int tid = threadIdx.x;
    int b = blockIdx.x;
    int s = boff[b], e = boff[b + 1];
    if (tid < 128) deg[tid] = 0;
    __syncthreads();
    for (int i = s + tid; i < e; i += 256) atomicAdd(&deg[ebuf[i] >> 16], 1);
    __syncthreads();
    if (tid == 0) {
        int run = s;
        for (int i = 0; i < 128; ++i) { curs[i] = run; run += deg[i]; }
    }
    __syncthreads();
    if (tid < 128) {
        int node = b * 128 + tid;
        if (node < NNODES) row_ptr[node] = curs[tid];
    }
    __syncthreads();
    for (int i = s + tid; i < e; i += 256) {
        unsigned pk = ebuf[i];
        int pos = atomicAdd(&curs[pk >> 16], 1);              // LDS atomic
        esrc[pos] = (int)(pk & 0xffffu);
    }
}

// ---------------- bf16 conversion of x and all 6 W matrices ----------------
__global__ void k_cvt(const float* __restrict__ x,
                      const float* __restrict__ w0, const float* __restrict__ w1,
                      const float* __restrict__ w2, const float* __restrict__ w3,
                      const float* __restrict__ w4, const float* __restrict__ w5,
                      unsigned short* __restrict__ xb, unsigned short* __restrict__ wb) {
    int gid = blockIdx.x * blockDim.x + threadIdx.x;
    const int NX = NNODES * NFEAT;
    if (gid < NX) {
        xb[gid] = f2bf(x[gid]);
    } else {
        int j = gid - NX;  // < 6*16384
        int m = j >> 14;
        int o = j & 16383;
        const float* w = (m == 0) ? w0 : (m == 1) ? w1 : (m == 2) ? w2
                       : (m == 3) ? w3 : (m == 4) ? w4 : w5;
        wb[j] = f2bf(w[o]);
    }
}

// ---------------- scatter-mean as CSR gather: wave per node ----------------
// Edge indices loaded coalesced per-lane, broadcast via shfl; 4 gathers in flight.
__global__ __launch_bounds__(256) void k_agg(const unsigned short* __restrict__ feat,
                                             const int* __restrict__ row_ptr,
                                             const int* __restrict__ esrc,
                                             unsigned short* __restrict__ agg) {
    int w = threadIdx.x >> 6;
    int l = threadIdx.x & 63;
    int n = blockIdx.x * 4 + w;
    if (n >= NNODES) return;
    int beg = row_ptr[n], end = row_ptr[n + 1];
    int nb = end - beg;
    const unsigned* feat32 = (const unsigned*)feat;  // 2 bf16 per dword, row stride 64
    float a0 = 0.f, a1 = 0.f;
    for (int base = 0; base < nb; base += 64) {
        int rem = nb - base;
        int cnt = rem < 64 ? rem : 64;
        int myidx = (l < cnt) ? esrc[beg + base + l] : 0;   // coalesced index load
        int j = 0;
        for (; j + 4 <= cnt; j += 4) {
            int s0 = __shfl(myidx, j);
            int s1 = __shfl(myidx, j + 1);
            int s2 = __shfl(myidx, j + 2);
            int s3 = __shfl(myidx, j + 3);
            unsigned v0 = feat32[s0 * 64 + l];
            unsigned v1 = feat32[s1 * 64 + l];
            unsigned v2 = feat32[s2 * 64 + l];
            unsigned v3 = feat32[s3 * 64 + l];
            a0 += (blo(v0) + blo(v1)) + (blo(v2) + blo(v3));
            a1 += (bhi(v0) + bhi(v1)) + (bhi(v2) + bhi(v3));
        }
        for (; j < cnt; ++j) {
            int s0 = __shfl(myidx, j);
            unsigned v0 = feat32[s0 * 64 + l];
            a0 += blo(v0);
            a1 += bhi(v0);
        }
    }
    float inv = 1.0f / (float)max(nb, 1);
    unsigned o = ((unsigned)f2bf(a0 * inv)) | (((unsigned)f2bf(a1 * inv)) << 16);
    ((unsigned*)agg)[n * 64 + l] = o;
}

// ---------------- fused dual-matvec GEMM: C = [agg|feat] @ [Wn|Ws]^T, +bias, relu ----
// v2: 8 waves/block, wave w owns output stripe nt=w (cols w*16..w*16+15).
// B fragments (8x short8 = 32 VGPR) loaded ONCE; loop 8 row-tiles of 16 rows.
// Per tile: 8 independent A loads -> 8 MFMAs; unroll lets compiler pipeline tiles.
__global__ __launch_bounds__(512) void k_gemm(const unsigned short* __restrict__ A1,
                                              const unsigned short* __restrict__ A2,
                                              const unsigned short* __restrict__ Bn,
                                              const unsigned short* __restrict__ Bs,
                                              const float* __restrict__ bias,
                                              unsigned short* __restrict__ out) {
    int wid = threadIdx.x >> 6;   // 0..7 = nt stripe
    int l = threadIdx.x & 63;
    int r = l & 15;               // row-in-tile for A, col-in-tile for B/C
    int gk = l >> 4;              // k-group (8 elements each)
    int m0 = blockIdx.x * 128;

    short8 bf[8];
    #pragma unroll
    for (int kt = 0; kt < 8; ++kt) {
        const unsigned short* Bbase = (kt < 4 ? Bn : Bs);
        int kk = (kt & 3) * 32 + gk * 8;
        bf[kt] = *(const short8*)(Bbase + (wid * 16 + r) * 128 + kk);
    }
    int o = wid * 16 + r;
    float bias_v = bias[o];

    #pragma unroll
    for (int rt = 0; rt < 8; ++rt) {
        int row = m0 + rt * 16 + r;
        int lrow = row < NNODES ? row : NNODES - 1;   // clamp loads; stores guarded
        short8 af[8];
        #pragma unroll
        for (int kt = 0; kt < 8; ++kt) {
            const unsigned short* Ap = (kt < 4 ? A1 : A2) + lrow * 128 + (kt & 3) * 32 + gk * 8;
            af[kt] = *(const short8*)Ap;
        }
        floatx4 acc = {0.f, 0.f, 0.f, 0.f};
        #pragma unroll
        for (int kt = 0; kt < 8; ++kt)
            acc = __builtin_amdgcn_mfma_f32_16x16x32_bf16(af[kt], bf[kt], acc, 0, 0, 0);
        // C/D layout: col = lane&15 (=r), row-in-tile = gk*4 + j
        #pragma unroll
        for (int j = 0; j < 4; ++j) {
            int mrow = m0 + rt * 16 + gk * 4 + j;
            if (mrow < NNODES) {
                float v = acc[j] + bias_v;
                v = v > 0.f ? v : 0.f;
                out[mrow * 128 + o] = f2bf(v);
            }
        }
    }
}

// ---------------- mean pool: 8 partial-sum blocks per graph ----------------
__global__ __launch_bounds__(256) void k_pool(const unsigned short* __restrict__ h,
                                              const int* __restrict__ gstart,
                                              float* __restrict__ part) {
    int g = blockIdx.x >> 3;
    int c = blockIdx.x & 7;
    int s = gstart[g], e = gstart[g + 1];
    int len = e - s;
    int cs = s + (len * c) / 8;
    int ce = s + (len * (c + 1)) / 8;
    int w = threadIdx.x >> 6;
    int l = threadIdx.x & 63;
    const unsigned* h32 = (const unsigned*)h;
    float a0 = 0.f, a1 = 0.f;
    for (int n = cs + w; n < ce; n += 4) {
        unsigned v = h32[n * 64 + l];
        a0 += blo(v);
        a1 += bhi(v);
    }
    __shared__ float red[4][128];
    red[w][2 * l] = a0;
    red[w][2 * l + 1] = a1;
    __syncthreads();
    if (w == 0) {
        float r0 = (red[0][2 * l] + red[1][2 * l]) + (red[2][2 * l] + red[3][2 * l]);
        float r1 = (red[0][2 * l + 1] + red[1][2 * l + 1]) + (red[2][2 * l + 1] + red[3][2 * l + 1]);
        float* dst = part + (size_t)(g * 8 + c) * 128;
        dst[2 * l] = r0;
        dst[2 * l + 1] = r1;
    }
}

// ---------------- head: reduce partials, logits + log_softmax (f32) ----------------
__global__ __launch_bounds__(128) void k_head(const float* __restrict__ part,
                                              const int* __restrict__ gstart,
                                              const float* __restrict__ Wlin,
                                              const float* __restrict__ blin,
                                              float* __restrict__ out) {
    int gi = blockIdx.x;
    __shared__ float gl[128];
    __shared__ float lg[NCLASS];
    int t = threadIdx.x;
    float s = 0.f;
    #pragma unroll
    for (int c = 0; c < 8; ++c) s += part[(size_t)(gi * 8 + c) * 128 + t];
    int len = gstart[gi + 1] - gstart[gi];
    gl[t] = s / (float)max(len, 1);
    __syncthreads();
    if (t < NCLASS) {
        float a = blin[t];
        #pragma unroll 16
        for (int i = 0; i < 128; ++i) a += gl[i] * Wlin[t * 128 + i];
        lg[t] = a;
    }
    __syncthreads();
    if (t == 0) {
        float m = lg[0];
        for (int k = 1; k < NCLASS; ++k) m = fmaxf(m, lg[k]);
        float sum = 0.f;
        for (int k = 0; k < NCLASS; ++k) sum += expf(lg[k] - m);
        float ls = logf(sum) + m;
        for (int k = 0; k < NCLASS; ++k) out[gi * NCLASS + k] = lg[k] - ls;
    }
}

extern "C" void kernel_launch(void* const* d_in, const int* in_sizes, int n_in,
                              void* d_out, int out_size, void* d_ws, size_t ws_size,
                              hipStream_t stream) {
    const float* x    = (const float*)d_in[0];
    const int*   ei   = (const int*)d_in[1];
    const int*   src  = ei;
    const int*   dst  = ei + NEDGES;
    const int*   batch= (const int*)d_in[2];
    const float* W1n  = (const float*)d_in[3];
    const float* b1   = (const float*)d_in[4];
    const float* W1s  = (const float*)d_in[5];
    const float* W2n  = (const float*)d_in[6];
    const float* b2   = (const float*)d_in[7];
    const float* W2s  = (const float*)d_in[8];
    const float* W3n  = (const float*)d_in[9];
    const float* b3   = (const float*)d_in[10];
    const float* W3s  = (const float*)d_in[11];
    const float* Wlin = (const float*)d_in[12];
    const float* blin = (const float*)d_in[13];
    float* out = (float*)d_out;

    char* p = (char*)d_ws;
    auto alloc = [&](size_t bytes) -> void* {
        void* r = (void*)p;
        p += (bytes + 255) & ~(size_t)255;
        return r;
    };
    unsigned short* xb   = (unsigned short*)alloc((size_t)NNODES * NFEAT * 2);
    unsigned short* hA   = (unsigned short*)alloc((size_t)NNODES * NHID * 2);
    unsigned short* hB   = (unsigned short*)alloc((size_t)NNODES * NHID * 2);
    unsigned short* agg  = (unsigned short*)alloc((size_t)NNODES * NHID * 2);
    unsigned short* wb   = (unsigned short*)alloc((size_t)6 * 16384 * 2);
    int* hist    = (int*)alloc((size_t)HB * NB * 4);
    int* base    = (int*)alloc((size_t)HB * NB * 4);
    int* boff    = (int*)alloc((size_t)(NB + 1) * 4);
    int* row_ptr = (int*)alloc((size_t)(NNODES + 1) * 4);
    int* gstart  = (int*)alloc((size_t)(NGRAPHS + 1) * 4);
    unsigned* ebuf = (unsigned*)alloc((size_t)NEDGES * 4);
    int* esrc    = (int*)alloc((size_t)NEDGES * 4);
    float* part  = (float*)alloc((size_t)NGRAPHS * 8 * NHID * 4);

    // CSR build (atomic-free counting sort) + graph ranges
    k_hist<<<HB, 256, 0, stream>>>(dst, hist);
    k_scan2<<<1, 512, 0, stream>>>(hist, base, boff, row_ptr, batch, gstart);
    k_scatter<<<HB, 256, 0, stream>>>(src, dst, base, ebuf);
    k_bcsr<<<NB, 256, 0, stream>>>(ebuf, boff, row_ptr, esrc);

    // convert x + weights to bf16
    {
        int total = NNODES * NFEAT + 6 * 16384;
        k_cvt<<<(total + 255) / 256, 256, 0, stream>>>(x, W1n, W1s, W2n, W2s, W3n, W3s, xb, wb);
    }

    const int aggGrid  = (NNODES + 3) / 4;
    const int gemmGrid = (NNODES + 127) / 128;

    // layer 1
    k_agg<<<aggGrid, 256, 0, stream>>>(xb, row_ptr, esrc, agg);
    k_gemm<<<gemmGrid, 512, 0, stream>>>(agg, xb, wb + 0 * 16384, wb + 1 * 16384, b1, hA);
    // layer 2
    k_agg<<<aggGrid, 256, 0, stream>>>(hA, row_ptr, esrc, agg);
    k_gemm<<<gemmGrid, 512, 0, stream>>>(agg, hA, wb + 2 * 16384, wb + 3 * 16384, b2, hB);
    // layer 3
    k_agg<<<aggGrid, 256, 0, stream>>>(hB, row_ptr, esrc, agg);
    k_gemm<<<gemmGrid, 512, 0, stream>>>(agg, hB, wb + 4 * 16384, wb + 5 * 16384, b3, hA);

    // pool + head
    k_pool<<<NGRAPHS * 8, 256, 0, stream>>>(hA, gstart, part);
    k_head<<<NGRAPHS, 128, 0, stream>>>(part, gstart, Wlin, blin, out);
}